// Round 14
// baseline (65.900 us; speedup 1.0000x reference)
//
#include <hip/hip_runtime.h>
#include <stdint.h>

typedef unsigned short u16;
typedef __attribute__((ext_vector_type(8))) __bf16 bf16x8;
typedef __attribute__((ext_vector_type(8))) unsigned short u16x8;
typedef __attribute__((ext_vector_type(4))) float f32x4;

#define AS1 __attribute__((address_space(1)))
#define AS3 __attribute__((address_space(3)))

__device__ __forceinline__ u16 f2bf(float f) {
  uint32_t u = __builtin_bit_cast(uint32_t, f);
  u += 0x7FFFu + ((u >> 16) & 1u);   // RNE; inputs are finite
  return (u16)(u >> 16);
}
__device__ __forceinline__ float bf2f(u16 h) {
  uint32_t u = ((uint32_t)h) << 16;
  return __builtin_bit_cast(float, u);
}
__device__ __forceinline__ void gload16(const void* g, void* l) {
  __builtin_amdgcn_global_load_lds((AS1 void*)g, (AS3 void*)l, 16, 0, 0);
}

// ---- fused: x f32->bf16 (blocks 0..4095) + w_qkv transpose (blocks 4096..4863) ----
__global__ __launch_bounds__(256) void prep(const float4* __restrict__ x,
                                            ushort4* __restrict__ x_bf,
                                            const float* __restrict__ w,
                                            u16* __restrict__ wt) {
  __shared__ u16 tile[32][33];
  const int bid = blockIdx.x;
  if (bid < 4096) {
    int i = bid * 256 + threadIdx.x;
    float4 v = x[i];
    ushort4 o;
    o.x = f2bf(v.x); o.y = f2bf(v.y); o.z = f2bf(v.z); o.w = f2bf(v.w);
    x_bf[i] = o;
  } else {
    int tb = bid - 4096;                 // 0..767 over [512][1536]
    int c0 = (tb % 48) * 32, r0 = (tb / 48) * 32;
    int tx = threadIdx.x & 31, ty = threadIdx.x >> 5;
    #pragma unroll
    for (int rr = ty; rr < 32; rr += 8)
      tile[rr][tx] = f2bf(w[(size_t)(r0 + rr) * 1536 + c0 + tx]);
    __syncthreads();
    #pragma unroll
    for (int rr = ty; rr < 32; rr += 8)
      wt[(size_t)(c0 + rr) * 512 + r0 + tx] = tile[tx][rr];
  }
}

// ---- bf16 GEMM: 128xBN tile, NWAVE waves (WR x WC wave grid), BK=64,
//      T2 LDS swizzle, T1 XCD swizzle, single-buffer 2-barrier schedule.
template<bool OUT_F32, bool BIAS, int NFRAG, int NWAVE, int WR, int WC>
__global__ __launch_bounds__(NWAVE * 64) void gemm_bt64(
    const u16* __restrict__ A, int lda, long long strideA,
    const u16* __restrict__ Bt, int ldb, long long strideB,
    void* __restrict__ C, int ldc, long long strideC,
    const float* __restrict__ bias, int K)
{
  constexpr int BN = NFRAG * 32;
  constexpr int MF = 128 / (WR * 16);         // m-fragments per wave
  constexpr int NF = BN / (WC * 16);          // n-fragments per wave
  constexpr int ASEG_W = 16 / NWAVE;          // A 8-row segments staged per wave
  constexpr int BSEG_W = (BN / 8) / NWAVE;    // B segments per wave
  static_assert(WR * WC == NWAVE, "wave grid");

  // T1: bijective XCD-chunked remap of the linear hw block id
  const int nwgx = gridDim.x, nwgy = gridDim.y;
  const int nwg = nwgx * nwgy * gridDim.z;
  const int hw = blockIdx.x + nwgx * (blockIdx.y + nwgy * blockIdx.z);
  const int cpx = nwg >> 3;
  const int swz = (hw & 7) * cpx + (hw >> 3);
  const int bx = swz % nwgx;
  const int tmp = swz / nwgx;
  const int by = tmp % nwgy;
  const int bz = tmp / nwgy;

  const int bcol = bx * BN;
  const int brow = by * 128;
  const u16* Ab = A + (size_t)bz * strideA;
  const u16* Bb = Bt + (size_t)bz * strideB;

  __shared__ u16 Asm[128 * 64];
  __shared__ u16 Bsm[BN * 64];

  const int tid = threadIdx.x;
  const int wid = tid >> 6;
  const int lane = tid & 63;
  const int fr = lane & 15, fq = lane >> 4;
  const int wr = wid / WC, wc = wid % WC;
  const int srow = lane >> 3;                 // 0..7 within an 8-row segment
  const int scol = ((lane & 7) ^ srow) * 8;   // T2 pre-swizzled source column
  const int xr = (fr & 7) * 8;                // read-side XOR (row&7)*8

  f32x4 acc[MF][NF];
  #pragma unroll
  for (int m = 0; m < MF; ++m)
    #pragma unroll
    for (int n = 0; n < NF; ++n)
      acc[m][n] = (f32x4)0.0f;

  for (int kt = 0; kt < K; kt += 64) {
    #pragma unroll
    for (int q = 0; q < ASEG_W; ++q) {
      int seg = wid * ASEG_W + q;             // 0..15, 8 rows each
      int row = seg * 8 + srow;
      gload16(Ab + (size_t)(brow + row) * lda + kt + scol, &Asm[seg * 512]);
    }
    #pragma unroll
    for (int q = 0; q < BSEG_W; ++q) {
      int seg = wid * BSEG_W + q;             // 0..BN/8-1
      int row = seg * 8 + srow;
      gload16(Bb + (size_t)(bcol + row) * ldb + kt + scol, &Bsm[seg * 512]);
    }
    __syncthreads();   // compiler drains vmcnt before s_barrier

    #pragma unroll
    for (int kk = 0; kk < 2; ++kk) {
      bf16x8 af[MF], bg[NF];
      #pragma unroll
      for (int m = 0; m < MF; ++m)
        af[m] = *(const bf16x8*)&Asm[(wr * (MF * 16) + m * 16 + fr) * 64 + ((kk * 32 + fq * 8) ^ xr)];
      #pragma unroll
      for (int n = 0; n < NF; ++n)
        bg[n] = *(const bf16x8*)&Bsm[(wc * (NF * 16) + n * 16 + fr) * 64 + ((kk * 32 + fq * 8) ^ xr)];
      #pragma unroll
      for (int m = 0; m < MF; ++m)
        #pragma unroll
        for (int n = 0; n < NF; ++n)
          acc[m][n] = __builtin_amdgcn_mfma_f32_16x16x32_bf16(af[m], bg[n], acc[m][n], 0, 0, 0);
    }
    __syncthreads();
  }

  #pragma unroll
  for (int m = 0; m < MF; ++m) {
    #pragma unroll
    for (int n = 0; n < NF; ++n) {
      #pragma unroll
      for (int j = 0; j < 4; ++j) {
        int row = brow + wr * (MF * 16) + m * 16 + fq * 4 + j;
        int col = bcol + wc * (NF * 16) + n * 16 + fr;
        float v = acc[m][n][j];
        if constexpr (OUT_F32) {
          if constexpr (BIAS) v += bias[col];
          ((float*)C)[(size_t)bz * strideC + (size_t)row * ldc + col] = v;
        } else {
          ((u16*)C)[(size_t)bz * strideC + (size_t)row * ldc + col] = f2bf(v);
        }
      }
    }
  }
}

// ---- per-(b,h) partial K^T V over a 128-row N-slice of qkv[8192][1536], MFMA ----
#define KTV_SPLIT 16
__global__ __launch_bounds__(256) void ktv_partial(const u16* __restrict__ qkv,
                                                   float* __restrict__ Mpart) {
  const int s = blockIdx.x;    // 0..15
  const int bh = blockIdx.y;   // 0..31
  const int b = bh >> 3, h = bh & 7;
  const int t = threadIdx.x;
  __shared__ alignas(16) u16 SM[2 * 64 * 136];
  u16* Kt = SM;
  u16* Vt = SM + 64 * 136;
  float* Msm = (float*)SM;

  const u16* base = qkv + (size_t)b * 2048 * 1536 + (size_t)(s * 128) * 1536;
  u16x8 v[8];
  #pragma unroll
  for (int it = 0; it < 8; ++it) {
    int c = it * 256 + t;
    int n = c >> 4, part = c & 15;
    int col = (part < 8) ? (512 + h * 64 + part * 8) : (1024 + h * 64 + (part - 8) * 8);
    v[it] = *(const u16x8*)(base + (size_t)n * 1536 + col);
  }
  #pragma unroll
  for (int it = 0; it < 8; ++it) {
    int c = it * 256 + t;
    int n = c >> 4, part = c & 15;
    int p8 = part & 7;
    u16* mat = (part < 8) ? Kt : Vt;
    int ncol = n ^ (p8 << 3);
    #pragma unroll
    for (int j = 0; j < 8; ++j)
      mat[(p8 * 8 + j) * 136 + ncol] = v[it][j];
  }
  __syncthreads();

  const int wid = t >> 6, lane = t & 63;
  const int fr = lane & 15, fq = lane >> 4;
  const int kbase = wid * 32 + fq * 8;
  f32x4 acc[4][4];
  #pragma unroll
  for (int m = 0; m < 4; ++m)
    #pragma unroll
    for (int n = 0; n < 4; ++n) acc[m][n] = (f32x4)0.0f;
  bf16x8 af[4], bg[4];
  #pragma unroll
  for (int m = 0; m < 4; ++m) {
    int d = m * 16 + fr;
    af[m] = *(const bf16x8*)&Kt[d * 136 + (kbase ^ ((d >> 3) << 3))];
  }
  #pragma unroll
  for (int n = 0; n < 4; ++n) {
    int e = n * 16 + fr;
    bg[n] = *(const bf16x8*)&Vt[e * 136 + (kbase ^ ((e >> 3) << 3))];
  }
  #pragma unroll
  for (int m = 0; m < 4; ++m)
    #pragma unroll
    for (int n = 0; n < 4; ++n)
      acc[m][n] = __builtin_amdgcn_mfma_f32_16x16x32_bf16(af[m], bg[n], acc[m][n], 0, 0, 0);
  __syncthreads();

  #pragma unroll
  for (int p = 0; p < 4; ++p) {
    if (wid == p) {
      #pragma unroll
      for (int m = 0; m < 4; ++m)
        #pragma unroll
        for (int n = 0; n < 4; ++n)
          #pragma unroll
          for (int j = 0; j < 4; ++j) {
            float* q = &Msm[(m * 16 + fq * 4 + j) * 64 + n * 16 + fr];
            *q = (p == 0) ? acc[m][n][j] : (*q + acc[m][n][j]);
          }
    }
    __syncthreads();
  }
  float4* d4 = (float4*)(Mpart + ((size_t)bh * KTV_SPLIT + s) * 4096);
  const float4* s4 = (const float4*)Msm;
  #pragma unroll
  for (int r = 0; r < 4; ++r) d4[t + r * 256] = s4[t + r * 256];
}

// ---- fused: reduce 16 partials of M_h in-LDS (L2-resident reads), then
//      Pt[b][c][h*64+d] = sum_e M[d][e] * w_out[h*64+e][c], bf16 ----
__global__ __launch_bounds__(256) void make_pt3(const float* __restrict__ Mpart,
                                                const float* __restrict__ w_out,
                                                u16* __restrict__ Pt, float scale) {
  const int ct = blockIdx.x;      // 0..7
  const int bh = blockIdx.y;      // 0..31
  const int b = bh >> 3, h = bh & 7;
  const int t = threadIdx.x;
  __shared__ float Msm[64 * 64];
  {
    const float4* src = (const float4*)(Mpart + (size_t)bh * KTV_SPLIT * 4096);
    float4* dst = (float4*)Msm;
    #pragma unroll
    for (int r = 0; r < 4; ++r) {
      int f4 = t + r * 256;
      float4 s; s.x = 0.f; s.y = 0.f; s.z = 0.f; s.w = 0.f;
      #pragma unroll 4
      for (int p = 0; p < KTV_SPLIT; ++p) {
        float4 g = src[p * 1024 + f4];
        s.x += g.x; s.y += g.y; s.z += g.z; s.w += g.w;
      }
      s.x *= scale; s.y *= scale; s.z *= scale; s.w *= scale;
      dst[f4] = s;
    }
  }
  __syncthreads();
  const int c = ct * 64 + (t & 63);
  const int d0 = (t >> 6) * 16;
  float acc[16];
  #pragma unroll
  for (int j = 0; j < 16; ++j) acc[j] = 0.f;
  const float* wcol = w_out + (size_t)h * 64 * 512 + c;
  #pragma unroll 4
  for (int e = 0; e < 64; ++e) {
    float w = wcol[(size_t)e * 512];
    #pragma unroll
    for (int j = 0; j < 16; ++j)
      acc[j] += Msm[(d0 + j) * 64 + e] * w;
  }
  ushort4 ov[4];
  #pragma unroll
  for (int r = 0; r < 4; ++r) {
    ov[r].x = f2bf(acc[r * 4 + 0]);
    ov[r].y = f2bf(acc[r * 4 + 1]);
    ov[r].z = f2bf(acc[r * 4 + 2]);
    ov[r].w = f2bf(acc[r * 4 + 3]);
  }
  ushort4* dst = (ushort4*)(Pt + (size_t)b * 262144 + (size_t)c * 512 + h * 64 + d0);
  #pragma unroll
  for (int r = 0; r < 4; ++r) dst[r] = ov[r];
}

extern "C" void kernel_launch(void* const* d_in, const int* in_sizes, int n_in,
                              void* d_out, int out_size, void* d_ws, size_t ws_size,
                              hipStream_t stream) {
  const float* x     = (const float*)d_in[0];   // [4,2048,512]
  const float* w_qkv = (const float*)d_in[1];   // [512,1536]
  const float* w_out = (const float*)d_in[2];   // [512,512]
  const float* b_out = (const float*)d_in[3];   // [512]
  float* out = (float*)d_out;                   // [4,2048,512] f32
  char* ws = (char*)d_ws;
  const long long MB = 1ll << 20;

  u16*   x_bf   = (u16*)(ws);                    // 8 MiB  [8192][512] bf16 (dead after GEMM1)
  u16*   wqkv_t = (u16*)(ws + 8 * MB);           // 1.5 MiB [1536][512] bf16 (w_qkv^T)
  u16*   qkv    = (u16*)(ws + 10 * MB);          // 24 MiB [8192][1536] bf16
  float* Mpart  = (float*)(ws + 34 * MB);        // 8 MiB  [32][16][64][64] f32
  u16*   Pt     = (u16*)(ws + 42 * MB);          // 2 MiB  [4][512][512] bf16 (P^T per b)

  // 1) x -> bf16 and w_qkv -> transposed bf16 (fused launch)
  prep<<<dim3(4096 + 768), dim3(256), 0, stream>>>(
      (const float4*)x, (ushort4*)x_bf, w_qkv, wqkv_t);
  // 2) qkv = x @ w_qkv  (M=8192, N=1536, K=512); 4-wave 128x96 tile
  gemm_bt64<false, false, 3, 4, 2, 2><<<dim3(16, 64, 1), dim3(256), 0, stream>>>(
      x_bf, 512, 0ll, wqkv_t, 512, 0ll, qkv, 1536, 0ll, nullptr, 512);
  // 3) partial K^T V per (b,h)  (MFMA version)
  ktv_partial<<<dim3(KTV_SPLIT, 32), dim3(256), 0, stream>>>(qkv, Mpart);
  // 4) Pt = (scale * M @ W_out)^T per (b,h); partials reduced in-block (L2-resident)
  make_pt3<<<dim3(8, 32), dim3(256), 0, stream>>>(Mpart, w_out, Pt, 0.125f / 2048.0f);
  // 5) out = Q_cat @ P + b_out (per b: M=2048, N=512, K=512); 8-wave 128x64
  gemm_bt64<true, true, 2, 8, 4, 2><<<dim3(8, 16, 4), dim3(512), 0, stream>>>(
      qkv, 1536, 2048ll * 1536, Pt, 512, 262144ll, out, 512, 2048ll * 512, b_out, 512);
}

// Round 15
// 60.412 us; speedup vs baseline: 1.0908x; 1.0908x over previous
//
#include <hip/hip_runtime.h>
#include <stdint.h>

typedef unsigned short u16;
typedef __attribute__((ext_vector_type(8))) __bf16 bf16x8;
typedef __attribute__((ext_vector_type(8))) unsigned short u16x8;
typedef __attribute__((ext_vector_type(4))) float f32x4;

#define AS1 __attribute__((address_space(1)))
#define AS3 __attribute__((address_space(3)))

__device__ __forceinline__ u16 f2bf(float f) {
  uint32_t u = __builtin_bit_cast(uint32_t, f);
  u += 0x7FFFu + ((u >> 16) & 1u);   // RNE; inputs are finite
  return (u16)(u >> 16);
}
__device__ __forceinline__ float bf2f(u16 h) {
  uint32_t u = ((uint32_t)h) << 16;
  return __builtin_bit_cast(float, u);
}
__device__ __forceinline__ void gload16(const void* g, void* l) {
  __builtin_amdgcn_global_load_lds((AS1 void*)g, (AS3 void*)l, 16, 0, 0);
}

// ---- fused: x f32->bf16 (blocks 0..4095) + w_qkv transpose (blocks 4096..4863) ----
__global__ __launch_bounds__(256) void prep(const float4* __restrict__ x,
                                            ushort4* __restrict__ x_bf,
                                            const float* __restrict__ w,
                                            u16* __restrict__ wt) {
  __shared__ u16 tile[32][33];
  const int bid = blockIdx.x;
  if (bid < 4096) {
    int i = bid * 256 + threadIdx.x;
    float4 v = x[i];
    ushort4 o;
    o.x = f2bf(v.x); o.y = f2bf(v.y); o.z = f2bf(v.z); o.w = f2bf(v.w);
    x_bf[i] = o;
  } else {
    int tb = bid - 4096;                 // 0..767 over [512][1536]
    int c0 = (tb % 48) * 32, r0 = (tb / 48) * 32;
    int tx = threadIdx.x & 31, ty = threadIdx.x >> 5;
    #pragma unroll
    for (int rr = ty; rr < 32; rr += 8)
      tile[rr][tx] = f2bf(w[(size_t)(r0 + rr) * 1536 + c0 + tx]);
    __syncthreads();
    #pragma unroll
    for (int rr = ty; rr < 32; rr += 8)
      wt[(size_t)(c0 + rr) * 512 + r0 + tx] = tile[tx][rr];
  }
}

// ---- bf16 GEMM: 128xBN tile, NWAVE waves (WR x WC wave grid), BK=64,
//      T2 LDS swizzle, T1 XCD swizzle. DBUF: double-buffered LDS with
//      prefetch-before-compute (one barrier/step); else single-buffer 2-barrier.
template<bool OUT_F32, bool BIAS, int NFRAG, int NWAVE, int WR, int WC, bool DBUF>
__global__ __launch_bounds__(NWAVE * 64) void gemm_bt64(
    const u16* __restrict__ A, int lda, long long strideA,
    const u16* __restrict__ Bt, int ldb, long long strideB,
    void* __restrict__ C, int ldc, long long strideC,
    const float* __restrict__ bias, int K)
{
  constexpr int BN = NFRAG * 32;
  constexpr int MF = 128 / (WR * 16);         // m-fragments per wave
  constexpr int NF = BN / (WC * 16);          // n-fragments per wave
  constexpr int ASEG_W = 16 / NWAVE;          // A 8-row segments staged per wave
  constexpr int BSEG_W = (BN / 8) / NWAVE;    // B segments per wave
  constexpr int NBUF = DBUF ? 2 : 1;
  static_assert(WR * WC == NWAVE, "wave grid");

  // T1: bijective XCD-chunked remap of the linear hw block id
  const int nwgx = gridDim.x, nwgy = gridDim.y;
  const int nwg = nwgx * nwgy * gridDim.z;
  const int hw = blockIdx.x + nwgx * (blockIdx.y + nwgy * blockIdx.z);
  const int cpx = nwg >> 3;
  const int swz = (hw & 7) * cpx + (hw >> 3);
  const int bx = swz % nwgx;
  const int tmp = swz / nwgx;
  const int by = tmp % nwgy;
  const int bz = tmp / nwgy;

  const int bcol = bx * BN;
  const int brow = by * 128;
  const u16* Ab = A + (size_t)bz * strideA;
  const u16* Bb = Bt + (size_t)bz * strideB;

  __shared__ u16 Asm[NBUF * 128 * 64];
  __shared__ u16 Bsm[NBUF * BN * 64];

  const int tid = threadIdx.x;
  const int wid = tid >> 6;
  const int lane = tid & 63;
  const int fr = lane & 15, fq = lane >> 4;
  const int wr = wid / WC, wc = wid % WC;
  const int srow = lane >> 3;                 // 0..7 within an 8-row segment
  const int scol = ((lane & 7) ^ srow) * 8;   // T2 pre-swizzled source column
  const int xr = (fr & 7) * 8;                // read-side XOR (row&7)*8

  f32x4 acc[MF][NF];
  #pragma unroll
  for (int m = 0; m < MF; ++m)
    #pragma unroll
    for (int n = 0; n < NF; ++n)
      acc[m][n] = (f32x4)0.0f;

  auto stage = [&](int buf, int kt) {
    #pragma unroll
    for (int q = 0; q < ASEG_W; ++q) {
      int seg = wid * ASEG_W + q;             // 0..15, 8 rows each
      int row = seg * 8 + srow;
      gload16(Ab + (size_t)(brow + row) * lda + kt + scol,
              &Asm[buf * (128 * 64) + seg * 512]);
    }
    #pragma unroll
    for (int q = 0; q < BSEG_W; ++q) {
      int seg = wid * BSEG_W + q;             // 0..BN/8-1
      int row = seg * 8 + srow;
      gload16(Bb + (size_t)(bcol + row) * ldb + kt + scol,
              &Bsm[buf * (BN * 64) + seg * 512]);
    }
  };
  auto compute = [&](int buf) {
    #pragma unroll
    for (int kk = 0; kk < 2; ++kk) {
      bf16x8 af[MF], bg[NF];
      #pragma unroll
      for (int m = 0; m < MF; ++m)
        af[m] = *(const bf16x8*)&Asm[buf * (128 * 64) +
                 (wr * (MF * 16) + m * 16 + fr) * 64 + ((kk * 32 + fq * 8) ^ xr)];
      #pragma unroll
      for (int n = 0; n < NF; ++n)
        bg[n] = *(const bf16x8*)&Bsm[buf * (BN * 64) +
                 (wc * (NF * 16) + n * 16 + fr) * 64 + ((kk * 32 + fq * 8) ^ xr)];
      #pragma unroll
      for (int m = 0; m < MF; ++m)
        #pragma unroll
        for (int n = 0; n < NF; ++n)
          acc[m][n] = __builtin_amdgcn_mfma_f32_16x16x32_bf16(af[m], bg[n], acc[m][n], 0, 0, 0);
    }
  };

  if constexpr (DBUF) {
    stage(0, 0);
    __syncthreads();                          // buf0 ready
    int cur = 0;
    for (int kt = 0; kt < K; kt += 64) {
      if (kt + 64 < K) stage(cur ^ 1, kt + 64);  // prefetch BEFORE compute
      compute(cur);
      __syncthreads();                        // one barrier/step: drains prefetch+ds
      cur ^= 1;
    }
  } else {
    for (int kt = 0; kt < K; kt += 64) {
      stage(0, kt);
      __syncthreads();                        // drain before compute
      compute(0);
      __syncthreads();
    }
  }

  #pragma unroll
  for (int m = 0; m < MF; ++m) {
    #pragma unroll
    for (int n = 0; n < NF; ++n) {
      #pragma unroll
      for (int j = 0; j < 4; ++j) {
        int row = brow + wr * (MF * 16) + m * 16 + fq * 4 + j;
        int col = bcol + wc * (NF * 16) + n * 16 + fr;
        float v = acc[m][n][j];
        if constexpr (OUT_F32) {
          if constexpr (BIAS) v += bias[col];
          ((float*)C)[(size_t)bz * strideC + (size_t)row * ldc + col] = v;
        } else {
          ((u16*)C)[(size_t)bz * strideC + (size_t)row * ldc + col] = f2bf(v);
        }
      }
    }
  }
}

// ---- per-(b,h) partial K^T V over a 128-row N-slice of qkv[8192][1536], MFMA ----
#define KTV_SPLIT 16
__global__ __launch_bounds__(256) void ktv_partial(const u16* __restrict__ qkv,
                                                   float* __restrict__ Mpart) {
  const int s = blockIdx.x;    // 0..15
  const int bh = blockIdx.y;   // 0..31
  const int b = bh >> 3, h = bh & 7;
  const int t = threadIdx.x;
  __shared__ alignas(16) u16 SM[2 * 64 * 136];
  u16* Kt = SM;
  u16* Vt = SM + 64 * 136;
  float* Msm = (float*)SM;

  const u16* base = qkv + (size_t)b * 2048 * 1536 + (size_t)(s * 128) * 1536;
  u16x8 v[8];
  #pragma unroll
  for (int it = 0; it < 8; ++it) {
    int c = it * 256 + t;
    int n = c >> 4, part = c & 15;
    int col = (part < 8) ? (512 + h * 64 + part * 8) : (1024 + h * 64 + (part - 8) * 8);
    v[it] = *(const u16x8*)(base + (size_t)n * 1536 + col);
  }
  #pragma unroll
  for (int it = 0; it < 8; ++it) {
    int c = it * 256 + t;
    int n = c >> 4, part = c & 15;
    int p8 = part & 7;
    u16* mat = (part < 8) ? Kt : Vt;
    int ncol = n ^ (p8 << 3);
    #pragma unroll
    for (int j = 0; j < 8; ++j)
      mat[(p8 * 8 + j) * 136 + ncol] = v[it][j];
  }
  __syncthreads();

  const int wid = t >> 6, lane = t & 63;
  const int fr = lane & 15, fq = lane >> 4;
  const int kbase = wid * 32 + fq * 8;
  f32x4 acc[4][4];
  #pragma unroll
  for (int m = 0; m < 4; ++m)
    #pragma unroll
    for (int n = 0; n < 4; ++n) acc[m][n] = (f32x4)0.0f;
  bf16x8 af[4], bg[4];
  #pragma unroll
  for (int m = 0; m < 4; ++m) {
    int d = m * 16 + fr;
    af[m] = *(const bf16x8*)&Kt[d * 136 + (kbase ^ ((d >> 3) << 3))];
  }
  #pragma unroll
  for (int n = 0; n < 4; ++n) {
    int e = n * 16 + fr;
    bg[n] = *(const bf16x8*)&Vt[e * 136 + (kbase ^ ((e >> 3) << 3))];
  }
  #pragma unroll
  for (int m = 0; m < 4; ++m)
    #pragma unroll
    for (int n = 0; n < 4; ++n)
      acc[m][n] = __builtin_amdgcn_mfma_f32_16x16x32_bf16(af[m], bg[n], acc[m][n], 0, 0, 0);
  __syncthreads();

  #pragma unroll
  for (int p = 0; p < 4; ++p) {
    if (wid == p) {
      #pragma unroll
      for (int m = 0; m < 4; ++m)
        #pragma unroll
        for (int n = 0; n < 4; ++n)
          #pragma unroll
          for (int j = 0; j < 4; ++j) {
            float* q = &Msm[(m * 16 + fq * 4 + j) * 64 + n * 16 + fr];
            *q = (p == 0) ? acc[m][n][j] : (*q + acc[m][n][j]);
          }
    }
    __syncthreads();
  }
  float4* d4 = (float4*)(Mpart + ((size_t)bh * KTV_SPLIT + s) * 4096);
  const float4* s4 = (const float4*)Msm;
  #pragma unroll
  for (int r = 0; r < 4; ++r) d4[t + r * 256] = s4[t + r * 256];
}

// ---- M[bh][d][e] = scale * sum_p Mpart[bh][p][d][e] ----
__global__ __launch_bounds__(256) void reduce_m(const float* __restrict__ Mpart,
                                                float* __restrict__ M, float scale) {
  int i = blockIdx.x * 256 + threadIdx.x;      // 0 .. 32*4096-1
  int bh = i >> 12;
  int off = i & 4095;
  const float* src = Mpart + ((size_t)bh * KTV_SPLIT) * 4096 + off;
  float s = 0.f;
  #pragma unroll
  for (int p = 0; p < KTV_SPLIT; ++p) s += src[(size_t)p * 4096];
  M[i] = s * scale;
}

// ---- Pt[b][c][h*64+d] = sum_e M[bh][d][e] * w_out[h*64+e][c], bf16 ----
__global__ __launch_bounds__(256) void make_pt2(const float* __restrict__ M,
                                                const float* __restrict__ w_out,
                                                u16* __restrict__ Pt) {
  const int ct = blockIdx.x;      // 0..7
  const int bh = blockIdx.y;      // 0..31
  const int b = bh >> 3, h = bh & 7;
  const int t = threadIdx.x;
  __shared__ float Msm[64 * 64];
  {
    const float4* src = (const float4*)(M + (size_t)bh * 4096);
    float4* dst = (float4*)Msm;
    #pragma unroll
    for (int r = 0; r < 4; ++r) dst[t + r * 256] = src[t + r * 256];
  }
  __syncthreads();
  const int c = ct * 64 + (t & 63);
  const int d0 = (t >> 6) * 16;
  float acc[16];
  #pragma unroll
  for (int j = 0; j < 16; ++j) acc[j] = 0.f;
  const float* wcol = w_out + (size_t)h * 64 * 512 + c;
  #pragma unroll 4
  for (int e = 0; e < 64; ++e) {
    float w = wcol[(size_t)e * 512];
    #pragma unroll
    for (int j = 0; j < 16; ++j)
      acc[j] += Msm[(d0 + j) * 64 + e] * w;
  }
  ushort4 ov[4];
  #pragma unroll
  for (int r = 0; r < 4; ++r) {
    ov[r].x = f2bf(acc[r * 4 + 0]);
    ov[r].y = f2bf(acc[r * 4 + 1]);
    ov[r].z = f2bf(acc[r * 4 + 2]);
    ov[r].w = f2bf(acc[r * 4 + 3]);
  }
  ushort4* dst = (ushort4*)(Pt + (size_t)b * 262144 + (size_t)c * 512 + h * 64 + d0);
  #pragma unroll
  for (int r = 0; r < 4; ++r) dst[r] = ov[r];
}

extern "C" void kernel_launch(void* const* d_in, const int* in_sizes, int n_in,
                              void* d_out, int out_size, void* d_ws, size_t ws_size,
                              hipStream_t stream) {
  const float* x     = (const float*)d_in[0];   // [4,2048,512]
  const float* w_qkv = (const float*)d_in[1];   // [512,1536]
  const float* w_out = (const float*)d_in[2];   // [512,512]
  const float* b_out = (const float*)d_in[3];   // [512]
  float* out = (float*)d_out;                   // [4,2048,512] f32
  char* ws = (char*)d_ws;
  const long long MB = 1ll << 20;

  u16*   x_bf   = (u16*)(ws);                    // 8 MiB  [8192][512] bf16 (dead after GEMM1)
  u16*   wqkv_t = (u16*)(ws + 8 * MB);           // 1.5 MiB [1536][512] bf16 (w_qkv^T)
  u16*   qkv    = (u16*)(ws + 10 * MB);          // 24 MiB [8192][1536] bf16
  float* Mpart  = (float*)(ws + 34 * MB);        // 8 MiB  [32][16][64][64] f32
  float* M      = (float*)(ws);                  // 0.5 MiB [32][64][64] f32 (reuses x_bf)
  u16*   Pt     = (u16*)(ws + 42 * MB);          // 2 MiB  [4][512][512] bf16 (P^T per b)

  // 1) x -> bf16 and w_qkv -> transposed bf16 (fused launch)
  prep<<<dim3(4096 + 768), dim3(256), 0, stream>>>(
      (const float4*)x, (ushort4*)x_bf, w_qkv, wqkv_t);
  // 2) qkv = x @ w_qkv  (M=8192, N=1536, K=512); 4-wave 128x96, single-buffer
  gemm_bt64<false, false, 3, 4, 2, 2, false><<<dim3(16, 64, 1), dim3(256), 0, stream>>>(
      x_bf, 512, 0ll, wqkv_t, 512, 0ll, qkv, 1536, 0ll, nullptr, 512);
  // 3) partial K^T V per (b,h)  (MFMA version)
  ktv_partial<<<dim3(KTV_SPLIT, 32), dim3(256), 0, stream>>>(qkv, Mpart);
  // 4) reduce partials
  reduce_m<<<dim3(512), dim3(256), 0, stream>>>(Mpart, M, 0.125f / 2048.0f);
  // 5) Pt = (M @ W_out)^T per (b,h)
  make_pt2<<<dim3(8, 32), dim3(256), 0, stream>>>(M, w_out, Pt);
  // 6) out = Q_cat @ P + b_out (per b); 8-wave 128x64, DOUBLE-BUFFERED
  //    (48 KB LDS; occupancy thread-capped at 2 blocks/CU either way)
  gemm_bt64<true, true, 2, 8, 4, 2, true><<<dim3(8, 16, 4), dim3(512), 0, stream>>>(
      qkv, 1536, 2048ll * 1536, Pt, 512, 262144ll, out, 512, 2048ll * 512, b_out, 512);
}

// Round 16
// 59.805 us; speedup vs baseline: 1.1019x; 1.0102x over previous
//
#include <hip/hip_runtime.h>
#include <stdint.h>

typedef unsigned short u16;
typedef __attribute__((ext_vector_type(8))) __bf16 bf16x8;
typedef __attribute__((ext_vector_type(8))) unsigned short u16x8;
typedef __attribute__((ext_vector_type(4))) float f32x4;

#define AS1 __attribute__((address_space(1)))
#define AS3 __attribute__((address_space(3)))

__device__ __forceinline__ u16 f2bf(float f) {
  uint32_t u = __builtin_bit_cast(uint32_t, f);
  u += 0x7FFFu + ((u >> 16) & 1u);   // RNE; inputs are finite
  return (u16)(u >> 16);
}
__device__ __forceinline__ float bf2f(u16 h) {
  uint32_t u = ((uint32_t)h) << 16;
  return __builtin_bit_cast(float, u);
}
__device__ __forceinline__ void gload16(const void* g, void* l) {
  __builtin_amdgcn_global_load_lds((AS1 void*)g, (AS3 void*)l, 16, 0, 0);
}

// ---- fused: x f32->bf16 (blocks 0..4095) + w_qkv transpose (blocks 4096..4863) ----
__global__ __launch_bounds__(256) void prep(const float4* __restrict__ x,
                                            ushort4* __restrict__ x_bf,
                                            const float* __restrict__ w,
                                            u16* __restrict__ wt) {
  __shared__ u16 tile[32][33];
  const int bid = blockIdx.x;
  if (bid < 4096) {
    int i = bid * 256 + threadIdx.x;
    float4 v = x[i];
    ushort4 o;
    o.x = f2bf(v.x); o.y = f2bf(v.y); o.z = f2bf(v.z); o.w = f2bf(v.w);
    x_bf[i] = o;
  } else {
    int tb = bid - 4096;                 // 0..767 over [512][1536]
    int c0 = (tb % 48) * 32, r0 = (tb / 48) * 32;
    int tx = threadIdx.x & 31, ty = threadIdx.x >> 5;
    #pragma unroll
    for (int rr = ty; rr < 32; rr += 8)
      tile[rr][tx] = f2bf(w[(size_t)(r0 + rr) * 1536 + c0 + tx]);
    __syncthreads();
    #pragma unroll
    for (int rr = ty; rr < 32; rr += 8)
      wt[(size_t)(c0 + rr) * 512 + r0 + tx] = tile[tx][rr];
  }
}

// ---- bf16 GEMM: 128xBN tile, NWAVE waves (WR x WC wave grid), BK=64,
//      T2 LDS swizzle, T1 XCD swizzle. DBUF: double-buffered LDS with
//      prefetch-before-compute (one barrier/step); else single-buffer 2-barrier.
template<bool OUT_F32, bool BIAS, int NFRAG, int NWAVE, int WR, int WC, bool DBUF>
__global__ __launch_bounds__(NWAVE * 64) void gemm_bt64(
    const u16* __restrict__ A, int lda, long long strideA,
    const u16* __restrict__ Bt, int ldb, long long strideB,
    void* __restrict__ C, int ldc, long long strideC,
    const float* __restrict__ bias, int K)
{
  constexpr int BN = NFRAG * 32;
  constexpr int MF = 128 / (WR * 16);         // m-fragments per wave
  constexpr int NF = BN / (WC * 16);          // n-fragments per wave
  constexpr int ASEG_W = 16 / NWAVE;          // A 8-row segments staged per wave
  constexpr int BSEG_W = (BN / 8) / NWAVE;    // B segments per wave
  constexpr int NBUF = DBUF ? 2 : 1;
  static_assert(WR * WC == NWAVE, "wave grid");

  // T1: bijective XCD-chunked remap of the linear hw block id
  const int nwgx = gridDim.x, nwgy = gridDim.y;
  const int nwg = nwgx * nwgy * gridDim.z;
  const int hw = blockIdx.x + nwgx * (blockIdx.y + nwgy * blockIdx.z);
  const int cpx = nwg >> 3;
  const int swz = (hw & 7) * cpx + (hw >> 3);
  const int bx = swz % nwgx;
  const int tmp = swz / nwgx;
  const int by = tmp % nwgy;
  const int bz = tmp / nwgy;

  const int bcol = bx * BN;
  const int brow = by * 128;
  const u16* Ab = A + (size_t)bz * strideA;
  const u16* Bb = Bt + (size_t)bz * strideB;

  __shared__ u16 Asm[NBUF * 128 * 64];
  __shared__ u16 Bsm[NBUF * BN * 64];

  const int tid = threadIdx.x;
  const int wid = tid >> 6;
  const int lane = tid & 63;
  const int fr = lane & 15, fq = lane >> 4;
  const int wr = wid / WC, wc = wid % WC;
  const int srow = lane >> 3;                 // 0..7 within an 8-row segment
  const int scol = ((lane & 7) ^ srow) * 8;   // T2 pre-swizzled source column
  const int xr = (fr & 7) * 8;                // read-side XOR (row&7)*8

  f32x4 acc[MF][NF];
  #pragma unroll
  for (int m = 0; m < MF; ++m)
    #pragma unroll
    for (int n = 0; n < NF; ++n)
      acc[m][n] = (f32x4)0.0f;

  auto stage = [&](int buf, int kt) {
    #pragma unroll
    for (int q = 0; q < ASEG_W; ++q) {
      int seg = wid * ASEG_W + q;             // 0..15, 8 rows each
      int row = seg * 8 + srow;
      gload16(Ab + (size_t)(brow + row) * lda + kt + scol,
              &Asm[buf * (128 * 64) + seg * 512]);
    }
    #pragma unroll
    for (int q = 0; q < BSEG_W; ++q) {
      int seg = wid * BSEG_W + q;             // 0..BN/8-1
      int row = seg * 8 + srow;
      gload16(Bb + (size_t)(bcol + row) * ldb + kt + scol,
              &Bsm[buf * (BN * 64) + seg * 512]);
    }
  };
  auto compute = [&](int buf) {
    #pragma unroll
    for (int kk = 0; kk < 2; ++kk) {
      bf16x8 af[MF], bg[NF];
      #pragma unroll
      for (int m = 0; m < MF; ++m)
        af[m] = *(const bf16x8*)&Asm[buf * (128 * 64) +
                 (wr * (MF * 16) + m * 16 + fr) * 64 + ((kk * 32 + fq * 8) ^ xr)];
      #pragma unroll
      for (int n = 0; n < NF; ++n)
        bg[n] = *(const bf16x8*)&Bsm[buf * (BN * 64) +
                 (wc * (NF * 16) + n * 16 + fr) * 64 + ((kk * 32 + fq * 8) ^ xr)];
      #pragma unroll
      for (int m = 0; m < MF; ++m)
        #pragma unroll
        for (int n = 0; n < NF; ++n)
          acc[m][n] = __builtin_amdgcn_mfma_f32_16x16x32_bf16(af[m], bg[n], acc[m][n], 0, 0, 0);
    }
  };

  if constexpr (DBUF) {
    stage(0, 0);
    __syncthreads();                          // buf0 ready
    int cur = 0;
    for (int kt = 0; kt < K; kt += 64) {
      if (kt + 64 < K) stage(cur ^ 1, kt + 64);  // prefetch BEFORE compute
      compute(cur);
      __syncthreads();                        // one barrier/step: drains prefetch+ds
      cur ^= 1;
    }
  } else {
    for (int kt = 0; kt < K; kt += 64) {
      stage(0, kt);
      __syncthreads();                        // drain before compute
      compute(0);
      __syncthreads();
    }
  }

  #pragma unroll
  for (int m = 0; m < MF; ++m) {
    #pragma unroll
    for (int n = 0; n < NF; ++n) {
      #pragma unroll
      for (int j = 0; j < 4; ++j) {
        int row = brow + wr * (MF * 16) + m * 16 + fq * 4 + j;
        int col = bcol + wc * (NF * 16) + n * 16 + fr;
        float v = acc[m][n][j];
        if constexpr (OUT_F32) {
          if constexpr (BIAS) v += bias[col];
          ((float*)C)[(size_t)bz * strideC + (size_t)row * ldc + col] = v;
        } else {
          ((u16*)C)[(size_t)bz * strideC + (size_t)row * ldc + col] = f2bf(v);
        }
      }
    }
  }
}

// ---- per-(b,h) partial K^T V over a 128-row N-slice of qkv[8192][1536], MFMA ----
#define KTV_SPLIT 16
__global__ __launch_bounds__(256) void ktv_partial(const u16* __restrict__ qkv,
                                                   float* __restrict__ Mpart) {
  const int s = blockIdx.x;    // 0..15
  const int bh = blockIdx.y;   // 0..31
  const int b = bh >> 3, h = bh & 7;
  const int t = threadIdx.x;
  __shared__ alignas(16) u16 SM[2 * 64 * 136];
  u16* Kt = SM;
  u16* Vt = SM + 64 * 136;
  float* Msm = (float*)SM;

  const u16* base = qkv + (size_t)b * 2048 * 1536 + (size_t)(s * 128) * 1536;
  u16x8 v[8];
  #pragma unroll
  for (int it = 0; it < 8; ++it) {
    int c = it * 256 + t;
    int n = c >> 4, part = c & 15;
    int col = (part < 8) ? (512 + h * 64 + part * 8) : (1024 + h * 64 + (part - 8) * 8);
    v[it] = *(const u16x8*)(base + (size_t)n * 1536 + col);
  }
  #pragma unroll
  for (int it = 0; it < 8; ++it) {
    int c = it * 256 + t;
    int n = c >> 4, part = c & 15;
    int p8 = part & 7;
    u16* mat = (part < 8) ? Kt : Vt;
    int ncol = n ^ (p8 << 3);
    #pragma unroll
    for (int j = 0; j < 8; ++j)
      mat[(p8 * 8 + j) * 136 + ncol] = v[it][j];
  }
  __syncthreads();

  const int wid = t >> 6, lane = t & 63;
  const int fr = lane & 15, fq = lane >> 4;
  const int kbase = wid * 32 + fq * 8;
  f32x4 acc[4][4];
  #pragma unroll
  for (int m = 0; m < 4; ++m)
    #pragma unroll
    for (int n = 0; n < 4; ++n) acc[m][n] = (f32x4)0.0f;
  bf16x8 af[4], bg[4];
  #pragma unroll
  for (int m = 0; m < 4; ++m) {
    int d = m * 16 + fr;
    af[m] = *(const bf16x8*)&Kt[d * 136 + (kbase ^ ((d >> 3) << 3))];
  }
  #pragma unroll
  for (int n = 0; n < 4; ++n) {
    int e = n * 16 + fr;
    bg[n] = *(const bf16x8*)&Vt[e * 136 + (kbase ^ ((e >> 3) << 3))];
  }
  #pragma unroll
  for (int m = 0; m < 4; ++m)
    #pragma unroll
    for (int n = 0; n < 4; ++n)
      acc[m][n] = __builtin_amdgcn_mfma_f32_16x16x32_bf16(af[m], bg[n], acc[m][n], 0, 0, 0);
  __syncthreads();

  #pragma unroll
  for (int p = 0; p < 4; ++p) {
    if (wid == p) {
      #pragma unroll
      for (int m = 0; m < 4; ++m)
        #pragma unroll
        for (int n = 0; n < 4; ++n)
          #pragma unroll
          for (int j = 0; j < 4; ++j) {
            float* q = &Msm[(m * 16 + fq * 4 + j) * 64 + n * 16 + fr];
            *q = (p == 0) ? acc[m][n][j] : (*q + acc[m][n][j]);
          }
    }
    __syncthreads();
  }
  float4* d4 = (float4*)(Mpart + ((size_t)bh * KTV_SPLIT + s) * 4096);
  const float4* s4 = (const float4*)Msm;
  #pragma unroll
  for (int r = 0; r < 4; ++r) d4[t + r * 256] = s4[t + r * 256];
}

// ---- M[bh][d][e] = scale * sum_p Mpart[bh][p][d][e] ----
__global__ __launch_bounds__(256) void reduce_m(const float* __restrict__ Mpart,
                                                float* __restrict__ M, float scale) {
  int i = blockIdx.x * 256 + threadIdx.x;      // 0 .. 32*4096-1
  int bh = i >> 12;
  int off = i & 4095;
  const float* src = Mpart + ((size_t)bh * KTV_SPLIT) * 4096 + off;
  float s = 0.f;
  #pragma unroll
  for (int p = 0; p < KTV_SPLIT; ++p) s += src[(size_t)p * 4096];
  M[i] = s * scale;
}

// ---- Pt[b][c][h*64+d] = sum_e M[bh][d][e] * w_out[h*64+e][c], bf16 ----
__global__ __launch_bounds__(256) void make_pt2(const float* __restrict__ M,
                                                const float* __restrict__ w_out,
                                                u16* __restrict__ Pt) {
  const int ct = blockIdx.x;      // 0..7
  const int bh = blockIdx.y;      // 0..31
  const int b = bh >> 3, h = bh & 7;
  const int t = threadIdx.x;
  __shared__ float Msm[64 * 64];
  {
    const float4* src = (const float4*)(M + (size_t)bh * 4096);
    float4* dst = (float4*)Msm;
    #pragma unroll
    for (int r = 0; r < 4; ++r) dst[t + r * 256] = src[t + r * 256];
  }
  __syncthreads();
  const int c = ct * 64 + (t & 63);
  const int d0 = (t >> 6) * 16;
  float acc[16];
  #pragma unroll
  for (int j = 0; j < 16; ++j) acc[j] = 0.f;
  const float* wcol = w_out + (size_t)h * 64 * 512 + c;
  #pragma unroll 4
  for (int e = 0; e < 64; ++e) {
    float w = wcol[(size_t)e * 512];
    #pragma unroll
    for (int j = 0; j < 16; ++j)
      acc[j] += Msm[(d0 + j) * 64 + e] * w;
  }
  ushort4 ov[4];
  #pragma unroll
  for (int r = 0; r < 4; ++r) {
    ov[r].x = f2bf(acc[r * 4 + 0]);
    ov[r].y = f2bf(acc[r * 4 + 1]);
    ov[r].z = f2bf(acc[r * 4 + 2]);
    ov[r].w = f2bf(acc[r * 4 + 3]);
  }
  ushort4* dst = (ushort4*)(Pt + (size_t)b * 262144 + (size_t)c * 512 + h * 64 + d0);
  #pragma unroll
  for (int r = 0; r < 4; ++r) dst[r] = ov[r];
}

extern "C" void kernel_launch(void* const* d_in, const int* in_sizes, int n_in,
                              void* d_out, int out_size, void* d_ws, size_t ws_size,
                              hipStream_t stream) {
  const float* x     = (const float*)d_in[0];   // [4,2048,512]
  const float* w_qkv = (const float*)d_in[1];   // [512,1536]
  const float* w_out = (const float*)d_in[2];   // [512,512]
  const float* b_out = (const float*)d_in[3];   // [512]
  float* out = (float*)d_out;                   // [4,2048,512] f32
  char* ws = (char*)d_ws;
  const long long MB = 1ll << 20;

  u16*   x_bf   = (u16*)(ws);                    // 8 MiB  [8192][512] bf16 (dead after GEMM1)
  u16*   wqkv_t = (u16*)(ws + 8 * MB);           // 1.5 MiB [1536][512] bf16 (w_qkv^T)
  u16*   qkv    = (u16*)(ws + 10 * MB);          // 24 MiB [8192][1536] bf16
  float* Mpart  = (float*)(ws + 34 * MB);        // 8 MiB  [32][16][64][64] f32
  float* M      = (float*)(ws);                  // 0.5 MiB [32][64][64] f32 (reuses x_bf)
  u16*   Pt     = (u16*)(ws + 42 * MB);          // 2 MiB  [4][512][512] bf16 (P^T per b)

  // 1) x -> bf16 and w_qkv -> transposed bf16 (fused launch)
  prep<<<dim3(4096 + 768), dim3(256), 0, stream>>>(
      (const float4*)x, (ushort4*)x_bf, w_qkv, wqkv_t);
  // 2) qkv = x @ w_qkv  (M=8192, N=1536, K=512); 8-wave 128x192 tile
  //    512 blocks = 2/CU, 16 waves/CU, 40KB LDS; 5 gloads + 24 MFMA per wave/K-step
  gemm_bt64<false, false, 6, 8, 2, 4, false><<<dim3(8, 64, 1), dim3(512), 0, stream>>>(
      x_bf, 512, 0ll, wqkv_t, 512, 0ll, qkv, 1536, 0ll, nullptr, 512);
  // 3) partial K^T V per (b,h)  (MFMA version)
  ktv_partial<<<dim3(KTV_SPLIT, 32), dim3(256), 0, stream>>>(qkv, Mpart);
  // 4) reduce partials
  reduce_m<<<dim3(512), dim3(256), 0, stream>>>(Mpart, M, 0.125f / 2048.0f);
  // 5) Pt = (M @ W_out)^T per (b,h)
  make_pt2<<<dim3(8, 32), dim3(256), 0, stream>>>(M, w_out, Pt);
  // 6) out = Q_cat @ P + b_out (per b); 8-wave 128x64, double-buffered
  gemm_bt64<true, true, 2, 8, 4, 2, true><<<dim3(8, 16, 4), dim3(512), 0, stream>>>(
      qkv, 1536, 2048ll * 1536, Pt, 512, 262144ll, out, 512, 2048ll * 512, b_out, 512);
}

// Round 17
// 58.981 us; speedup vs baseline: 1.1173x; 1.0140x over previous
//
#include <hip/hip_runtime.h>
#include <stdint.h>

typedef unsigned short u16;
typedef __attribute__((ext_vector_type(8))) __bf16 bf16x8;
typedef __attribute__((ext_vector_type(8))) unsigned short u16x8;
typedef __attribute__((ext_vector_type(4))) float f32x4;

#define AS1 __attribute__((address_space(1)))
#define AS3 __attribute__((address_space(3)))

__device__ __forceinline__ u16 f2bf(float f) {
  uint32_t u = __builtin_bit_cast(uint32_t, f);
  u += 0x7FFFu + ((u >> 16) & 1u);   // RNE; inputs are finite
  return (u16)(u >> 16);
}
__device__ __forceinline__ float bf2f(u16 h) {
  uint32_t u = ((uint32_t)h) << 16;
  return __builtin_bit_cast(float, u);
}
__device__ __forceinline__ void gload16(const void* g, void* l) {
  __builtin_amdgcn_global_load_lds((AS1 void*)g, (AS3 void*)l, 16, 0, 0);
}

// ---- fused: x f32->bf16 (blocks 0..4095) + w_qkv transpose (blocks 4096..4863) ----
__global__ __launch_bounds__(256) void prep(const float4* __restrict__ x,
                                            ushort4* __restrict__ x_bf,
                                            const float* __restrict__ w,
                                            u16* __restrict__ wt) {
  __shared__ u16 tile[32][33];
  const int bid = blockIdx.x;
  if (bid < 4096) {
    int i = bid * 256 + threadIdx.x;
    float4 v = x[i];
    ushort4 o;
    o.x = f2bf(v.x); o.y = f2bf(v.y); o.z = f2bf(v.z); o.w = f2bf(v.w);
    x_bf[i] = o;
  } else {
    int tb = bid - 4096;                 // 0..767 over [512][1536]
    int c0 = (tb % 48) * 32, r0 = (tb / 48) * 32;
    int tx = threadIdx.x & 31, ty = threadIdx.x >> 5;
    #pragma unroll
    for (int rr = ty; rr < 32; rr += 8)
      tile[rr][tx] = f2bf(w[(size_t)(r0 + rr) * 1536 + c0 + tx]);
    __syncthreads();
    #pragma unroll
    for (int rr = ty; rr < 32; rr += 8)
      wt[(size_t)(c0 + rr) * 512 + r0 + tx] = tile[tx][rr];
  }
}

// ---- bf16 GEMM: 128xBN tile, NWAVE waves (WR x WC wave grid), BK=64,
//      T2 LDS swizzle, T1 XCD swizzle. DBUF: double-buffered LDS with
//      prefetch-before-compute (one barrier/step); else single-buffer 2-barrier.
template<bool OUT_F32, bool BIAS, int NFRAG, int NWAVE, int WR, int WC, bool DBUF>
__global__ __launch_bounds__(NWAVE * 64) void gemm_bt64(
    const u16* __restrict__ A, int lda, long long strideA,
    const u16* __restrict__ Bt, int ldb, long long strideB,
    void* __restrict__ C, int ldc, long long strideC,
    const float* __restrict__ bias, int K)
{
  constexpr int BN = NFRAG * 32;
  constexpr int MF = 128 / (WR * 16);         // m-fragments per wave
  constexpr int NF = BN / (WC * 16);          // n-fragments per wave
  constexpr int ASEG_W = 16 / NWAVE;          // A 8-row segments staged per wave
  constexpr int BSEG_W = (BN / 8) / NWAVE;    // B segments per wave
  constexpr int NBUF = DBUF ? 2 : 1;
  static_assert(WR * WC == NWAVE, "wave grid");

  // T1: bijective XCD-chunked remap of the linear hw block id
  const int nwgx = gridDim.x, nwgy = gridDim.y;
  const int nwg = nwgx * nwgy * gridDim.z;
  const int hw = blockIdx.x + nwgx * (blockIdx.y + nwgy * blockIdx.z);
  const int cpx = nwg >> 3;
  const int swz = (hw & 7) * cpx + (hw >> 3);
  const int bx = swz % nwgx;
  const int tmp = swz / nwgx;
  const int by = tmp % nwgy;
  const int bz = tmp / nwgy;

  const int bcol = bx * BN;
  const int brow = by * 128;
  const u16* Ab = A + (size_t)bz * strideA;
  const u16* Bb = Bt + (size_t)bz * strideB;

  __shared__ u16 Asm[NBUF * 128 * 64];
  __shared__ u16 Bsm[NBUF * BN * 64];

  const int tid = threadIdx.x;
  const int wid = tid >> 6;
  const int lane = tid & 63;
  const int fr = lane & 15, fq = lane >> 4;
  const int wr = wid / WC, wc = wid % WC;
  const int srow = lane >> 3;                 // 0..7 within an 8-row segment
  const int scol = ((lane & 7) ^ srow) * 8;   // T2 pre-swizzled source column
  const int xr = (fr & 7) * 8;                // read-side XOR (row&7)*8

  f32x4 acc[MF][NF];
  #pragma unroll
  for (int m = 0; m < MF; ++m)
    #pragma unroll
    for (int n = 0; n < NF; ++n)
      acc[m][n] = (f32x4)0.0f;

  auto stage = [&](int buf, int kt) {
    #pragma unroll
    for (int q = 0; q < ASEG_W; ++q) {
      int seg = wid * ASEG_W + q;             // 0..15, 8 rows each
      int row = seg * 8 + srow;
      gload16(Ab + (size_t)(brow + row) * lda + kt + scol,
              &Asm[buf * (128 * 64) + seg * 512]);
    }
    #pragma unroll
    for (int q = 0; q < BSEG_W; ++q) {
      int seg = wid * BSEG_W + q;             // 0..BN/8-1
      int row = seg * 8 + srow;
      gload16(Bb + (size_t)(bcol + row) * ldb + kt + scol,
              &Bsm[buf * (BN * 64) + seg * 512]);
    }
  };
  auto compute = [&](int buf) {
    #pragma unroll
    for (int kk = 0; kk < 2; ++kk) {
      bf16x8 af[MF], bg[NF];
      #pragma unroll
      for (int m = 0; m < MF; ++m)
        af[m] = *(const bf16x8*)&Asm[buf * (128 * 64) +
                 (wr * (MF * 16) + m * 16 + fr) * 64 + ((kk * 32 + fq * 8) ^ xr)];
      #pragma unroll
      for (int n = 0; n < NF; ++n)
        bg[n] = *(const bf16x8*)&Bsm[buf * (BN * 64) +
                 (wc * (NF * 16) + n * 16 + fr) * 64 + ((kk * 32 + fq * 8) ^ xr)];
      #pragma unroll
      for (int m = 0; m < MF; ++m)
        #pragma unroll
        for (int n = 0; n < NF; ++n)
          acc[m][n] = __builtin_amdgcn_mfma_f32_16x16x32_bf16(af[m], bg[n], acc[m][n], 0, 0, 0);
    }
  };

  if constexpr (DBUF) {
    stage(0, 0);
    __syncthreads();                          // buf0 ready
    int cur = 0;
    for (int kt = 0; kt < K; kt += 64) {
      if (kt + 64 < K) stage(cur ^ 1, kt + 64);  // prefetch BEFORE compute
      compute(cur);
      __syncthreads();                        // one barrier/step: drains prefetch+ds
      cur ^= 1;
    }
  } else {
    for (int kt = 0; kt < K; kt += 64) {
      stage(0, kt);
      __syncthreads();                        // drain before compute
      compute(0);
      __syncthreads();
    }
  }

  #pragma unroll
  for (int m = 0; m < MF; ++m) {
    #pragma unroll
    for (int n = 0; n < NF; ++n) {
      #pragma unroll
      for (int j = 0; j < 4; ++j) {
        int row = brow + wr * (MF * 16) + m * 16 + fq * 4 + j;
        int col = bcol + wc * (NF * 16) + n * 16 + fr;
        float v = acc[m][n][j];
        if constexpr (OUT_F32) {
          if constexpr (BIAS) v += bias[col];
          ((float*)C)[(size_t)bz * strideC + (size_t)row * ldc + col] = v;
        } else {
          ((u16*)C)[(size_t)bz * strideC + (size_t)row * ldc + col] = f2bf(v);
        }
      }
    }
  }
}

// ---- per-(b,h) partial K^T V over a 128-row N-slice of qkv[8192][1536], MFMA ----
#define KTV_SPLIT 16
__global__ __launch_bounds__(256) void ktv_partial(const u16* __restrict__ qkv,
                                                   float* __restrict__ Mpart) {
  const int s = blockIdx.x;    // 0..15
  const int bh = blockIdx.y;   // 0..31
  const int b = bh >> 3, h = bh & 7;
  const int t = threadIdx.x;
  __shared__ alignas(16) u16 SM[2 * 64 * 136];
  u16* Kt = SM;
  u16* Vt = SM + 64 * 136;
  float* Msm = (float*)SM;

  const u16* base = qkv + (size_t)b * 2048 * 1536 + (size_t)(s * 128) * 1536;
  u16x8 v[8];
  #pragma unroll
  for (int it = 0; it < 8; ++it) {
    int c = it * 256 + t;
    int n = c >> 4, part = c & 15;
    int col = (part < 8) ? (512 + h * 64 + part * 8) : (1024 + h * 64 + (part - 8) * 8);
    v[it] = *(const u16x8*)(base + (size_t)n * 1536 + col);
  }
  #pragma unroll
  for (int it = 0; it < 8; ++it) {
    int c = it * 256 + t;
    int n = c >> 4, part = c & 15;
    int p8 = part & 7;
    u16* mat = (part < 8) ? Kt : Vt;
    int ncol = n ^ (p8 << 3);
    #pragma unroll
    for (int j = 0; j < 8; ++j)
      mat[(p8 * 8 + j) * 136 + ncol] = v[it][j];
  }
  __syncthreads();

  const int wid = t >> 6, lane = t & 63;
  const int fr = lane & 15, fq = lane >> 4;
  const int kbase = wid * 32 + fq * 8;
  f32x4 acc[4][4];
  #pragma unroll
  for (int m = 0; m < 4; ++m)
    #pragma unroll
    for (int n = 0; n < 4; ++n) acc[m][n] = (f32x4)0.0f;
  bf16x8 af[4], bg[4];
  #pragma unroll
  for (int m = 0; m < 4; ++m) {
    int d = m * 16 + fr;
    af[m] = *(const bf16x8*)&Kt[d * 136 + (kbase ^ ((d >> 3) << 3))];
  }
  #pragma unroll
  for (int n = 0; n < 4; ++n) {
    int e = n * 16 + fr;
    bg[n] = *(const bf16x8*)&Vt[e * 136 + (kbase ^ ((e >> 3) << 3))];
  }
  #pragma unroll
  for (int m = 0; m < 4; ++m)
    #pragma unroll
    for (int n = 0; n < 4; ++n)
      acc[m][n] = __builtin_amdgcn_mfma_f32_16x16x32_bf16(af[m], bg[n], acc[m][n], 0, 0, 0);
  __syncthreads();

  #pragma unroll
  for (int p = 0; p < 4; ++p) {
    if (wid == p) {
      #pragma unroll
      for (int m = 0; m < 4; ++m)
        #pragma unroll
        for (int n = 0; n < 4; ++n)
          #pragma unroll
          for (int j = 0; j < 4; ++j) {
            float* q = &Msm[(m * 16 + fq * 4 + j) * 64 + n * 16 + fr];
            *q = (p == 0) ? acc[m][n][j] : (*q + acc[m][n][j]);
          }
    }
    __syncthreads();
  }
  float4* d4 = (float4*)(Mpart + ((size_t)bh * KTV_SPLIT + s) * 4096);
  const float4* s4 = (const float4*)Msm;
  #pragma unroll
  for (int r = 0; r < 4; ++r) d4[t + r * 256] = s4[t + r * 256];
}

// ---- M[bh][d][e] = scale * sum_p Mpart[bh][p][d][e] ----
__global__ __launch_bounds__(256) void reduce_m(const float* __restrict__ Mpart,
                                                float* __restrict__ M, float scale) {
  int i = blockIdx.x * 256 + threadIdx.x;      // 0 .. 32*4096-1
  int bh = i >> 12;
  int off = i & 4095;
  const float* src = Mpart + ((size_t)bh * KTV_SPLIT) * 4096 + off;
  float s = 0.f;
  #pragma unroll
  for (int p = 0; p < KTV_SPLIT; ++p) s += src[(size_t)p * 4096];
  M[i] = s * scale;
}

// ---- Pt[b][c][h*64+d] = sum_e M[bh][d][e] * w_out[h*64+e][c], bf16 ----
__global__ __launch_bounds__(256) void make_pt2(const float* __restrict__ M,
                                                const float* __restrict__ w_out,
                                                u16* __restrict__ Pt) {
  const int ct = blockIdx.x;      // 0..7
  const int bh = blockIdx.y;      // 0..31
  const int b = bh >> 3, h = bh & 7;
  const int t = threadIdx.x;
  __shared__ float Msm[64 * 64];
  {
    const float4* src = (const float4*)(M + (size_t)bh * 4096);
    float4* dst = (float4*)Msm;
    #pragma unroll
    for (int r = 0; r < 4; ++r) dst[t + r * 256] = src[t + r * 256];
  }
  __syncthreads();
  const int c = ct * 64 + (t & 63);
  const int d0 = (t >> 6) * 16;
  float acc[16];
  #pragma unroll
  for (int j = 0; j < 16; ++j) acc[j] = 0.f;
  const float* wcol = w_out + (size_t)h * 64 * 512 + c;
  #pragma unroll 4
  for (int e = 0; e < 64; ++e) {
    float w = wcol[(size_t)e * 512];
    #pragma unroll
    for (int j = 0; j < 16; ++j)
      acc[j] += Msm[(d0 + j) * 64 + e] * w;
  }
  ushort4 ov[4];
  #pragma unroll
  for (int r = 0; r < 4; ++r) {
    ov[r].x = f2bf(acc[r * 4 + 0]);
    ov[r].y = f2bf(acc[r * 4 + 1]);
    ov[r].z = f2bf(acc[r * 4 + 2]);
    ov[r].w = f2bf(acc[r * 4 + 3]);
  }
  ushort4* dst = (ushort4*)(Pt + (size_t)b * 262144 + (size_t)c * 512 + h * 64 + d0);
  #pragma unroll
  for (int r = 0; r < 4; ++r) dst[r] = ov[r];
}

extern "C" void kernel_launch(void* const* d_in, const int* in_sizes, int n_in,
                              void* d_out, int out_size, void* d_ws, size_t ws_size,
                              hipStream_t stream) {
  const float* x     = (const float*)d_in[0];   // [4,2048,512]
  const float* w_qkv = (const float*)d_in[1];   // [512,1536]
  const float* w_out = (const float*)d_in[2];   // [512,512]
  const float* b_out = (const float*)d_in[3];   // [512]
  float* out = (float*)d_out;                   // [4,2048,512] f32
  char* ws = (char*)d_ws;
  const long long MB = 1ll << 20;

  u16*   x_bf   = (u16*)(ws);                    // 8 MiB  [8192][512] bf16 (dead after GEMM1)
  u16*   wqkv_t = (u16*)(ws + 8 * MB);           // 1.5 MiB [1536][512] bf16 (w_qkv^T)
  u16*   qkv    = (u16*)(ws + 10 * MB);          // 24 MiB [8192][1536] bf16
  float* Mpart  = (float*)(ws + 34 * MB);        // 8 MiB  [32][16][64][64] f32
  float* M      = (float*)(ws);                  // 0.5 MiB [32][64][64] f32 (reuses x_bf)
  u16*   Pt     = (u16*)(ws + 42 * MB);          // 2 MiB  [4][512][512] bf16 (P^T per b)

  // 1) x -> bf16 and w_qkv -> transposed bf16 (fused launch)
  prep<<<dim3(4096 + 768), dim3(256), 0, stream>>>(
      (const float4*)x, (ushort4*)x_bf, w_qkv, wqkv_t);
  // 2) qkv = x @ w_qkv  (M=8192, N=1536, K=512); 8-wave 128x192, DOUBLE-BUFFERED
  //    80KB LDS x 2 blocks/CU = 160KB exact; occupancy preserved, prefetch overlap added
  gemm_bt64<false, false, 6, 8, 2, 4, true><<<dim3(8, 64, 1), dim3(512), 0, stream>>>(
      x_bf, 512, 0ll, wqkv_t, 512, 0ll, qkv, 1536, 0ll, nullptr, 512);
  // 3) partial K^T V per (b,h)  (MFMA version)
  ktv_partial<<<dim3(KTV_SPLIT, 32), dim3(256), 0, stream>>>(qkv, Mpart);
  // 4) reduce partials
  reduce_m<<<dim3(512), dim3(256), 0, stream>>>(Mpart, M, 0.125f / 2048.0f);
  // 5) Pt = (M @ W_out)^T per (b,h)
  make_pt2<<<dim3(8, 32), dim3(256), 0, stream>>>(M, w_out, Pt);
  // 6) out = Q_cat @ P + b_out (per b); 8-wave 128x64, double-buffered
  gemm_bt64<true, true, 2, 8, 4, 2, true><<<dim3(8, 16, 4), dim3(512), 0, stream>>>(
      qkv, 1536, 2048ll * 1536, Pt, 512, 262144ll, out, 512, 2048ll * 512, b_out, 512);
}

// Round 18
// 56.468 us; speedup vs baseline: 1.1670x; 1.0445x over previous
//
#include <hip/hip_runtime.h>
#include <stdint.h>

typedef unsigned short u16;
typedef __attribute__((ext_vector_type(8))) __bf16 bf16x8;
typedef __attribute__((ext_vector_type(8))) unsigned short u16x8;
typedef __attribute__((ext_vector_type(4))) float f32x4;

#define AS1 __attribute__((address_space(1)))
#define AS3 __attribute__((address_space(3)))

__device__ __forceinline__ u16 f2bf(float f) {
  uint32_t u = __builtin_bit_cast(uint32_t, f);
  u += 0x7FFFu + ((u >> 16) & 1u);   // RNE; inputs are finite
  return (u16)(u >> 16);
}
__device__ __forceinline__ float bf2f(u16 h) {
  uint32_t u = ((uint32_t)h) << 16;
  return __builtin_bit_cast(float, u);
}
__device__ __forceinline__ void gload16(const void* g, void* l) {
  __builtin_amdgcn_global_load_lds((AS1 void*)g, (AS3 void*)l, 16, 0, 0);
}

// ---- fused: x f32->bf16 (blocks 0..4095) + w_qkv transpose (blocks 4096..4863) ----
__global__ __launch_bounds__(256) void prep(const float4* __restrict__ x,
                                            ushort4* __restrict__ x_bf,
                                            const float* __restrict__ w,
                                            u16* __restrict__ wt) {
  __shared__ u16 tile[32][33];
  const int bid = blockIdx.x;
  if (bid < 4096) {
    int i = bid * 256 + threadIdx.x;
    float4 v = x[i];
    ushort4 o;
    o.x = f2bf(v.x); o.y = f2bf(v.y); o.z = f2bf(v.z); o.w = f2bf(v.w);
    x_bf[i] = o;
  } else {
    int tb = bid - 4096;                 // 0..767 over [512][1536]
    int c0 = (tb % 48) * 32, r0 = (tb / 48) * 32;
    int tx = threadIdx.x & 31, ty = threadIdx.x >> 5;
    #pragma unroll
    for (int rr = ty; rr < 32; rr += 8)
      tile[rr][tx] = f2bf(w[(size_t)(r0 + rr) * 1536 + c0 + tx]);
    __syncthreads();
    #pragma unroll
    for (int rr = ty; rr < 32; rr += 8)
      wt[(size_t)(c0 + rr) * 512 + r0 + tx] = tile[tx][rr];
  }
}

// ---- bf16 GEMM: 128xBN tile, NWAVE waves (WR x WC wave grid), BK=64,
//      T2 LDS swizzle, T1 XCD swizzle. DBUF: double-buffered LDS with
//      prefetch-before-compute (one barrier/step); else single-buffer 2-barrier.
template<bool OUT_F32, bool BIAS, int NFRAG, int NWAVE, int WR, int WC, bool DBUF>
__global__ __launch_bounds__(NWAVE * 64) void gemm_bt64(
    const u16* __restrict__ A, int lda, long long strideA,
    const u16* __restrict__ Bt, int ldb, long long strideB,
    void* __restrict__ C, int ldc, long long strideC,
    const float* __restrict__ bias, int K)
{
  constexpr int BN = NFRAG * 32;
  constexpr int MF = 128 / (WR * 16);         // m-fragments per wave
  constexpr int NF = BN / (WC * 16);          // n-fragments per wave
  constexpr int ASEG_W = 16 / NWAVE;          // A 8-row segments staged per wave
  constexpr int BSEG_W = (BN / 8) / NWAVE;    // B segments per wave
  constexpr int NBUF = DBUF ? 2 : 1;
  static_assert(WR * WC == NWAVE, "wave grid");

  // T1: bijective XCD-chunked remap of the linear hw block id
  const int nwgx = gridDim.x, nwgy = gridDim.y;
  const int nwg = nwgx * nwgy * gridDim.z;
  const int hw = blockIdx.x + nwgx * (blockIdx.y + nwgy * blockIdx.z);
  const int cpx = nwg >> 3;
  const int swz = (hw & 7) * cpx + (hw >> 3);
  const int bx = swz % nwgx;
  const int tmp = swz / nwgx;
  const int by = tmp % nwgy;
  const int bz = tmp / nwgy;

  const int bcol = bx * BN;
  const int brow = by * 128;
  const u16* Ab = A + (size_t)bz * strideA;
  const u16* Bb = Bt + (size_t)bz * strideB;

  __shared__ u16 Asm[NBUF * 128 * 64];
  __shared__ u16 Bsm[NBUF * BN * 64];

  const int tid = threadIdx.x;
  const int wid = tid >> 6;
  const int lane = tid & 63;
  const int fr = lane & 15, fq = lane >> 4;
  const int wr = wid / WC, wc = wid % WC;
  const int srow = lane >> 3;                 // 0..7 within an 8-row segment
  const int scol = ((lane & 7) ^ srow) * 8;   // T2 pre-swizzled source column
  const int xr = (fr & 7) * 8;                // read-side XOR (row&7)*8

  f32x4 acc[MF][NF];
  #pragma unroll
  for (int m = 0; m < MF; ++m)
    #pragma unroll
    for (int n = 0; n < NF; ++n)
      acc[m][n] = (f32x4)0.0f;

  auto stage = [&](int buf, int kt) {
    #pragma unroll
    for (int q = 0; q < ASEG_W; ++q) {
      int seg = wid * ASEG_W + q;             // 0..15, 8 rows each
      int row = seg * 8 + srow;
      gload16(Ab + (size_t)(brow + row) * lda + kt + scol,
              &Asm[buf * (128 * 64) + seg * 512]);
    }
    #pragma unroll
    for (int q = 0; q < BSEG_W; ++q) {
      int seg = wid * BSEG_W + q;             // 0..BN/8-1
      int row = seg * 8 + srow;
      gload16(Bb + (size_t)(bcol + row) * ldb + kt + scol,
              &Bsm[buf * (BN * 64) + seg * 512]);
    }
  };
  auto compute = [&](int buf) {
    #pragma unroll
    for (int kk = 0; kk < 2; ++kk) {
      bf16x8 af[MF], bg[NF];
      #pragma unroll
      for (int m = 0; m < MF; ++m)
        af[m] = *(const bf16x8*)&Asm[buf * (128 * 64) +
                 (wr * (MF * 16) + m * 16 + fr) * 64 + ((kk * 32 + fq * 8) ^ xr)];
      #pragma unroll
      for (int n = 0; n < NF; ++n)
        bg[n] = *(const bf16x8*)&Bsm[buf * (BN * 64) +
                 (wc * (NF * 16) + n * 16 + fr) * 64 + ((kk * 32 + fq * 8) ^ xr)];
      #pragma unroll
      for (int m = 0; m < MF; ++m)
        #pragma unroll
        for (int n = 0; n < NF; ++n)
          acc[m][n] = __builtin_amdgcn_mfma_f32_16x16x32_bf16(af[m], bg[n], acc[m][n], 0, 0, 0);
    }
  };

  if constexpr (DBUF) {
    stage(0, 0);
    __syncthreads();                          // buf0 ready
    int cur = 0;
    for (int kt = 0; kt < K; kt += 64) {
      if (kt + 64 < K) stage(cur ^ 1, kt + 64);  // prefetch BEFORE compute
      compute(cur);
      __syncthreads();                        // one barrier/step: drains prefetch+ds
      cur ^= 1;
    }
  } else {
    for (int kt = 0; kt < K; kt += 64) {
      stage(0, kt);
      __syncthreads();                        // drain before compute
      compute(0);
      __syncthreads();
    }
  }

  #pragma unroll
  for (int m = 0; m < MF; ++m) {
    #pragma unroll
    for (int n = 0; n < NF; ++n) {
      #pragma unroll
      for (int j = 0; j < 4; ++j) {
        int row = brow + wr * (MF * 16) + m * 16 + fq * 4 + j;
        int col = bcol + wc * (NF * 16) + n * 16 + fr;
        float v = acc[m][n][j];
        if constexpr (OUT_F32) {
          if constexpr (BIAS) v += bias[col];
          ((float*)C)[(size_t)bz * strideC + (size_t)row * ldc + col] = v;
        } else {
          ((u16*)C)[(size_t)bz * strideC + (size_t)row * ldc + col] = f2bf(v);
        }
      }
    }
  }
}

// ---- per-(b,h) partial K^T V over a 128-row N-slice of qkv[8192][1536], MFMA.
//      Cross-wave reduce: concurrent per-wave quadrant writes + register tree-sum
//      (replaces the 4-turn serial loop; 5 barriers -> 3; 64KB LDS keeps 2 blocks/CU).
#define KTV_SPLIT 16
__global__ __launch_bounds__(256) void ktv_partial(const u16* __restrict__ qkv,
                                                   float* __restrict__ Mpart) {
  const int s = blockIdx.x;    // 0..15
  const int bh = blockIdx.y;   // 0..31
  const int b = bh >> 3, h = bh & 7;
  const int t = threadIdx.x;
  __shared__ alignas(16) float SMF[4 * 4096];   // 64 KB: stage (34KB) then 4 quadrants
  u16* Kt = (u16*)SMF;
  u16* Vt = (u16*)SMF + 64 * 136;

  const u16* base = qkv + (size_t)b * 2048 * 1536 + (size_t)(s * 128) * 1536;
  u16x8 v[8];
  #pragma unroll
  for (int it = 0; it < 8; ++it) {
    int c = it * 256 + t;
    int n = c >> 4, part = c & 15;
    int col = (part < 8) ? (512 + h * 64 + part * 8) : (1024 + h * 64 + (part - 8) * 8);
    v[it] = *(const u16x8*)(base + (size_t)n * 1536 + col);
  }
  #pragma unroll
  for (int it = 0; it < 8; ++it) {
    int c = it * 256 + t;
    int n = c >> 4, part = c & 15;
    int p8 = part & 7;
    u16* mat = (part < 8) ? Kt : Vt;
    int ncol = n ^ (p8 << 3);
    #pragma unroll
    for (int j = 0; j < 8; ++j)
      mat[(p8 * 8 + j) * 136 + ncol] = v[it][j];
  }
  __syncthreads();

  const int wid = t >> 6, lane = t & 63;
  const int fr = lane & 15, fq = lane >> 4;
  const int kbase = wid * 32 + fq * 8;
  f32x4 acc[4][4];
  #pragma unroll
  for (int m = 0; m < 4; ++m)
    #pragma unroll
    for (int n = 0; n < 4; ++n) acc[m][n] = (f32x4)0.0f;
  bf16x8 af[4], bg[4];
  #pragma unroll
  for (int m = 0; m < 4; ++m) {
    int d = m * 16 + fr;
    af[m] = *(const bf16x8*)&Kt[d * 136 + (kbase ^ ((d >> 3) << 3))];
  }
  #pragma unroll
  for (int n = 0; n < 4; ++n) {
    int e = n * 16 + fr;
    bg[n] = *(const bf16x8*)&Vt[e * 136 + (kbase ^ ((e >> 3) << 3))];
  }
  #pragma unroll
  for (int m = 0; m < 4; ++m)
    #pragma unroll
    for (int n = 0; n < 4; ++n)
      acc[m][n] = __builtin_amdgcn_mfma_f32_16x16x32_bf16(af[m], bg[n], acc[m][n], 0, 0, 0);
  __syncthreads();                         // all LDS stage-reads complete

  // concurrent per-wave quadrant writes (disjoint 16 KB regions)
  float* myq = SMF + wid * 4096;
  #pragma unroll
  for (int m = 0; m < 4; ++m)
    #pragma unroll
    for (int n = 0; n < 4; ++n)
      #pragma unroll
      for (int j = 0; j < 4; ++j)
        myq[(m * 16 + fq * 4 + j) * 64 + n * 16 + fr] = acc[m][n][j];
  __syncthreads();

  // register tree-sum of 4 quadrants (same add order as old serial loop), write global
  const float4* q0 = (const float4*)SMF;
  float4* d4 = (float4*)(Mpart + ((size_t)bh * KTV_SPLIT + s) * 4096);
  #pragma unroll
  for (int r = 0; r < 4; ++r) {
    int f4 = t + r * 256;
    float4 a = q0[f4], b1 = q0[1024 + f4], c2 = q0[2048 + f4], d3 = q0[3072 + f4];
    float4 o;
    o.x = ((a.x + b1.x) + c2.x) + d3.x;
    o.y = ((a.y + b1.y) + c2.y) + d3.y;
    o.z = ((a.z + b1.z) + c2.z) + d3.z;
    o.w = ((a.w + b1.w) + c2.w) + d3.w;
    d4[f4] = o;
  }
}

// ---- M[bh][d][e] = scale * sum_p Mpart[bh][p][d][e] ----
__global__ __launch_bounds__(256) void reduce_m(const float* __restrict__ Mpart,
                                                float* __restrict__ M, float scale) {
  int i = blockIdx.x * 256 + threadIdx.x;      // 0 .. 32*4096-1
  int bh = i >> 12;
  int off = i & 4095;
  const float* src = Mpart + ((size_t)bh * KTV_SPLIT) * 4096 + off;
  float s = 0.f;
  #pragma unroll
  for (int p = 0; p < KTV_SPLIT; ++p) s += src[(size_t)p * 4096];
  M[i] = s * scale;
}

// ---- Pt[b][c][h*64+d] = sum_e M[bh][d][e] * w_out[h*64+e][c], bf16 ----
__global__ __launch_bounds__(256) void make_pt2(const float* __restrict__ M,
                                                const float* __restrict__ w_out,
                                                u16* __restrict__ Pt) {
  const int ct = blockIdx.x;      // 0..7
  const int bh = blockIdx.y;      // 0..31
  const int b = bh >> 3, h = bh & 7;
  const int t = threadIdx.x;
  __shared__ float Msm[64 * 64];
  {
    const float4* src = (const float4*)(M + (size_t)bh * 4096);
    float4* dst = (float4*)Msm;
    #pragma unroll
    for (int r = 0; r < 4; ++r) dst[t + r * 256] = src[t + r * 256];
  }
  __syncthreads();
  const int c = ct * 64 + (t & 63);
  const int d0 = (t >> 6) * 16;
  float acc[16];
  #pragma unroll
  for (int j = 0; j < 16; ++j) acc[j] = 0.f;
  const float* wcol = w_out + (size_t)h * 64 * 512 + c;
  #pragma unroll 4
  for (int e = 0; e < 64; ++e) {
    float w = wcol[(size_t)e * 512];
    #pragma unroll
    for (int j = 0; j < 16; ++j)
      acc[j] += Msm[(d0 + j) * 64 + e] * w;
  }
  ushort4 ov[4];
  #pragma unroll
  for (int r = 0; r < 4; ++r) {
    ov[r].x = f2bf(acc[r * 4 + 0]);
    ov[r].y = f2bf(acc[r * 4 + 1]);
    ov[r].z = f2bf(acc[r * 4 + 2]);
    ov[r].w = f2bf(acc[r * 4 + 3]);
  }
  ushort4* dst = (ushort4*)(Pt + (size_t)b * 262144 + (size_t)c * 512 + h * 64 + d0);
  #pragma unroll
  for (int r = 0; r < 4; ++r) dst[r] = ov[r];
}

extern "C" void kernel_launch(void* const* d_in, const int* in_sizes, int n_in,
                              void* d_out, int out_size, void* d_ws, size_t ws_size,
                              hipStream_t stream) {
  const float* x     = (const float*)d_in[0];   // [4,2048,512]
  const float* w_qkv = (const float*)d_in[1];   // [512,1536]
  const float* w_out = (const float*)d_in[2];   // [512,512]
  const float* b_out = (const float*)d_in[3];   // [512]
  float* out = (float*)d_out;                   // [4,2048,512] f32
  char* ws = (char*)d_ws;
  const long long MB = 1ll << 20;

  u16*   x_bf   = (u16*)(ws);                    // 8 MiB  [8192][512] bf16 (dead after GEMM1)
  u16*   wqkv_t = (u16*)(ws + 8 * MB);           // 1.5 MiB [1536][512] bf16 (w_qkv^T)
  u16*   qkv    = (u16*)(ws + 10 * MB);          // 24 MiB [8192][1536] bf16
  float* Mpart  = (float*)(ws + 34 * MB);        // 8 MiB  [32][16][64][64] f32
  float* M      = (float*)(ws);                  // 0.5 MiB [32][64][64] f32 (reuses x_bf)
  u16*   Pt     = (u16*)(ws + 42 * MB);          // 2 MiB  [4][512][512] bf16 (P^T per b)

  // 1) x -> bf16 and w_qkv -> transposed bf16 (fused launch)
  prep<<<dim3(4096 + 768), dim3(256), 0, stream>>>(
      (const float4*)x, (ushort4*)x_bf, w_qkv, wqkv_t);
  // 2) qkv = x @ w_qkv  (M=8192, N=1536, K=512); 8-wave 128x192, double-buffered
  gemm_bt64<false, false, 6, 8, 2, 4, true><<<dim3(8, 64, 1), dim3(512), 0, stream>>>(
      x_bf, 512, 0ll, wqkv_t, 512, 0ll, qkv, 1536, 0ll, nullptr, 512);
  // 3) partial K^T V per (b,h)  (MFMA + parallel cross-wave reduce)
  ktv_partial<<<dim3(KTV_SPLIT, 32), dim3(256), 0, stream>>>(qkv, Mpart);
  // 4) reduce partials
  reduce_m<<<dim3(512), dim3(256), 0, stream>>>(Mpart, M, 0.125f / 2048.0f);
  // 5) Pt = (M @ W_out)^T per (b,h)
  make_pt2<<<dim3(8, 32), dim3(256), 0, stream>>>(M, w_out, Pt);
  // 6) out = Q_cat @ P + b_out (per b); 8-wave 128x64, double-buffered
  gemm_bt64<true, true, 2, 8, 4, 2, true><<<dim3(8, 16, 4), dim3(512), 0, stream>>>(
      qkv, 1536, 2048ll * 1536, Pt, 512, 262144ll, out, 512, 2048ll * 512, b_out, 512);
}